// Round 8
// baseline (90.374 us; speedup 1.0000x reference)
//
#include <hip/hip_runtime.h>

#define EPS 1e-5f
constexpr float INV_N1 = 1.f / 524288.f;   // D*U*2
constexpr float INV_N3 = 1.f / 262144.f;   // D*U

__device__ __forceinline__ float lrelu(float y) { return fmaxf(y, 0.01f * y); }

template <int CTRL>
__device__ __forceinline__ float dppMov(float v) {
    return __int_as_float(__builtin_amdgcn_update_dpp(
        0, __float_as_int(v), CTRL, 0xF, 0xF, true));
}
// sum within each 16-lane row; valid at lane%16==15
__device__ __forceinline__ float rowSumDpp(float v) {
    v += dppMov<0x111>(v);
    v += dppMov<0x112>(v);
    v += dppMov<0x114>(v);
    v += dppMov<0x118>(v);
    return v;
}
// sum over each 4-lane quad (all quad lanes get it)
__device__ __forceinline__ float quadSum(float v) {
    v += dppMov<0xB1>(v);   // quad_perm xor1
    v += dppMov<0x4E>(v);   // quad_perm xor2
    return v;
}
__device__ __forceinline__ float waveAllSum(float v) {
    v += __shfl_xor(v, 32); v += __shfl_xor(v, 16); v += __shfl_xor(v, 8);
    v += __shfl_xor(v, 4);  v += __shfl_xor(v, 2);  v += __shfl_xor(v, 1);
    return v;
}

// ---------------------------------------------------------------------------
// kA: 640 blocks.
//  [0,512):   per-d sums of w1/b1 -> S1,S2,S11,S0b,Sb2 (plain stores)
//  [512,576): partial column sums of g3/be3 -> Gp/Bp (plain stores)
//  [576,640): LN0 per batch -> xn, Xs
// ---------------------------------------------------------------------------
__global__ void __launch_bounds__(256) kA(
    const float* __restrict__ w1, const float* __restrict__ b1,
    const float* __restrict__ g3, const float* __restrict__ be3,
    const float* __restrict__ x, const float* __restrict__ g0,
    const float* __restrict__ be0,
    float* __restrict__ S1, float* __restrict__ S2, float* __restrict__ S11,
    float* __restrict__ S0b, float* __restrict__ Sb2,
    float* __restrict__ Gp, float* __restrict__ Bp,
    float* __restrict__ xnp, float* __restrict__ Xs) {
    int bid = blockIdx.x, tid = threadIdx.x;
    int wave = tid >> 6, lane = tid & 63;
    __shared__ float red[4][5];
    __shared__ float bc[2];
    if (bid < 512) {
        const float4* wr = (const float4*)(w1 + bid * 1024);
        const float4* br = (const float4*)(b1 + bid * 1024);
        float4 w = wr[tid], b = br[tid];
        float s1  = w.x + w.y + w.z + w.w;
        float s2  = w.x * w.x + w.y * w.y + w.z * w.z + w.w * w.w;
        float s11 = w.x * b.x + w.y * b.y + w.z * b.z + w.w * b.w;
        float s0  = b.x + b.y + b.z + b.w;
        float sb2 = b.x * b.x + b.y * b.y + b.z * b.z + b.w * b.w;
        s1 = waveAllSum(s1); s2 = waveAllSum(s2); s11 = waveAllSum(s11);
        s0 = waveAllSum(s0); sb2 = waveAllSum(sb2);
        if (lane == 0) {
            red[wave][0] = s1; red[wave][1] = s2; red[wave][2] = s11;
            red[wave][3] = s0; red[wave][4] = sb2;
        }
        __syncthreads();
        if (tid == 0) {
            float a0 = 0, a1 = 0, a2 = 0, a3 = 0, a4 = 0;
            for (int w4 = 0; w4 < 4; ++w4) {
                a0 += red[w4][0]; a1 += red[w4][1]; a2 += red[w4][2];
                a3 += red[w4][3]; a4 += red[w4][4];
            }
            S1[bid] = a0; S2[bid] = a1; S11[bid] = a2;
            S0b[bid] = a3; Sb2[bid] = a4;
        }
    } else if (bid < 576) {
        int jj = bid - 512;   // 0..63, 8 d-rows each
        float ag0 = 0, ag1 = 0, ab0 = 0, ab1 = 0;
#pragma unroll
        for (int r = 0; r < 8; ++r) {
            const float* gr = g3 + (jj * 8 + r) * 512;
            const float* br = be3 + (jj * 8 + r) * 512;
            ag0 += gr[tid];  ag1 += gr[tid + 256];
            ab0 += br[tid];  ab1 += br[tid + 256];
        }
        Gp[jj * 512 + tid] = ag0; Gp[jj * 512 + tid + 256] = ag1;
        Bp[jj * 512 + tid] = ab0; Bp[jj * 512 + tid + 256] = ab1;
    } else {
        int b = bid - 576;
        float2 xv = ((const float2*)(x + b * 512))[tid];
        float sx = xv.x + xv.y, sxx = xv.x * xv.x + xv.y * xv.y;
        sx = waveAllSum(sx); sxx = waveAllSum(sxx);
        if (lane == 0) { red[wave][0] = sx; red[wave][1] = sxx; }
        __syncthreads();
        if (tid == 0) {
            float s = red[0][0] + red[1][0] + red[2][0] + red[3][0];
            float c = red[0][1] + red[1][1] + red[2][1] + red[3][1];
            float m = s * (1.f / 512.f);
            float var = c * (1.f / 512.f) - m * m;
            bc[0] = m; bc[1] = rsqrtf(var + EPS);
        }
        __syncthreads();
        float m = bc[0], rsd = bc[1];
        float2 g = ((const float2*)g0)[tid], be = ((const float2*)be0)[tid];
        float xn0 = (xv.x - m) * rsd * g.x + be.x;
        float xn1 = (xv.y - m) * rsd * g.y + be.y;
        ((float2*)(xnp + b * 512))[tid] = make_float2(xn0, xn1);
        float sxn = waveAllSum(xn0 + xn1);
        __syncthreads();
        if (lane == 0) red[wave][0] = sxn;
        __syncthreads();
        if (tid == 0) Xs[b] = red[0][0] + red[1][0] + red[2][0] + red[3][0];
    }
}

// ---------------------------------------------------------------------------
// k1: 512 blocks (d = bid).
// Prologue: redundant per-block LN1 stats — 3 dot products over d per batch
// (xn.S1, xn^2.S2 + 2 xn.S11, + constants) -> scA/scB in LDS; block 0 also
// publishes rs1a/mm1a for k2.
// Main: LN2 stat partials (ILP-2 over u-slots), rowSumDpp, one barrier,
// coalesced plain store part1[bid][128].
// ---------------------------------------------------------------------------
__global__ void __launch_bounds__(256) k1(
    const float* __restrict__ w1, const float* __restrict__ b1,
    const float* __restrict__ g1, const float* __restrict__ be1,
    const float* __restrict__ w21, const float* __restrict__ w22,
    const float* __restrict__ b21, const float* __restrict__ b22,
    const float* __restrict__ xnp,
    const float* __restrict__ S1, const float* __restrict__ S2,
    const float* __restrict__ S11, const float* __restrict__ S0b,
    const float* __restrict__ Sb2,
    float* __restrict__ rs1a, float* __restrict__ mm1a,
    float* __restrict__ part1) {
    int bid = blockIdx.x, tid = threadIdx.x;
    int d = bid;
    int wave = tid >> 6, lane = tid & 63;
    __shared__ float xcol[64], scA[64], scB[64];
    __shared__ float2 red2[64][4][4];   // [b][wave][row]
    __shared__ float stat2[64][2];
    __shared__ float redc[4][2];
    __shared__ float cbc[2];
    // ---- prologue: LN1 stats (dot products over dot-index dd = tid, tid+256)
    {
        float s1a = S1[tid],  s1b = S1[tid + 256];
        float s2a = S2[tid],  s2b = S2[tid + 256];
        float sca = S11[tid], scb = S11[tid + 256];
        float cs0 = S0b[tid] + S0b[tid + 256];
        float csb = Sb2[tid] + Sb2[tid + 256];
        cs0 = waveAllSum(cs0); csb = waveAllSum(csb);
        if (lane == 0) { redc[wave][0] = cs0; redc[wave][1] = csb; }
        for (int b = 0; b < 64; ++b) {
            float xn0 = xnp[b * 512 + tid], xn1 = xnp[b * 512 + tid + 256];
            float pm = fmaf(xn0, s1a, xn1 * s1b);
            float pe = xn0 * xn0 * s2a + 2.f * xn0 * sca
                     + xn1 * xn1 * s2b + 2.f * xn1 * scb;
            pm = rowSumDpp(pm);
            pe = rowSumDpp(pe);
            if ((lane & 15) == 15)
                red2[b][wave][lane >> 4] = make_float2(pm, pe);
        }
        __syncthreads();
        if (tid == 0)
            cbc[0] = redc[0][0] + redc[1][0] + redc[2][0] + redc[3][0];
        else if (tid == 1)
            cbc[1] = redc[0][1] + redc[1][1] + redc[2][1] + redc[3][1];
        if (tid < 128) {
            int b = tid >> 1, k = tid & 1;
            float s = 0;
#pragma unroll
            for (int w = 0; w < 4; ++w)
#pragma unroll
                for (int r = 0; r < 4; ++r)
                    s += ((const float*)&red2[b][w][r])[k];
            stat2[b][k] = s;
        }
        __syncthreads();
        if (tid < 64) {
            float pm = stat2[tid][0] + cbc[0];
            float pe = stat2[tid][1] + cbc[1];
            float m1 = pm * INV_N1, e1 = pe * INV_N1;
            float r = rsqrtf(e1 - m1 * m1 + EPS);
            scA[tid] = r; scB[tid] = m1 * r;
            xcol[tid] = xnp[tid * 512 + d];
            if (bid == 0) { rs1a[tid] = r; mm1a[tid] = m1 * r; }
        }
    }
    // ---- main loop
    int i0 = d * 512 + tid, i1 = i0 + 256;
    float2 W1a = ((const float2*)w1)[i0], B1a = ((const float2*)b1)[i0];
    float2 G1a = ((const float2*)g1)[i0], E1a = ((const float2*)be1)[i0];
    float2 Aa  = ((const float2*)w21)[i0], Ca = ((const float2*)w22)[i0];
    float Baa = b21[i0], Bca = b22[i0];
    float2 W1b = ((const float2*)w1)[i1], B1b = ((const float2*)b1)[i1];
    float2 G1b = ((const float2*)g1)[i1], E1b = ((const float2*)be1)[i1];
    float2 Ab  = ((const float2*)w21)[i1], Cb = ((const float2*)w22)[i1];
    float Bab = b21[i1], Bcb = b22[i1];
    __syncthreads();
    for (int b = 0; b < 64; ++b) {
        float xd = xcol[b], r1 = scA[b], mmv = scB[b];
        float t0 = fmaf(xd, W1a.x, B1a.x), t1 = fmaf(xd, W1a.y, B1a.y);
        float z0 = fmaf(t0, r1, -mmv), z1 = fmaf(t1, r1, -mmv);
        float y0 = fmaf(z0, G1a.x, E1a.x), y1 = fmaf(z1, G1a.y, E1a.y);
        float l0 = lrelu(y0), l1 = lrelu(y1);
        float c0 = fmaf(l0, Aa.x, fmaf(l1, Aa.y, Baa));
        float c1 = fmaf(l0, Ca.x, fmaf(l1, Ca.y, Bca));
        float v1 = c0 + c1;
        float v2 = fmaf(c0, c0, c1 * c1);
        t0 = fmaf(xd, W1b.x, B1b.x); t1 = fmaf(xd, W1b.y, B1b.y);
        z0 = fmaf(t0, r1, -mmv); z1 = fmaf(t1, r1, -mmv);
        y0 = fmaf(z0, G1b.x, E1b.x); y1 = fmaf(z1, G1b.y, E1b.y);
        l0 = lrelu(y0); l1 = lrelu(y1);
        c0 = fmaf(l0, Ab.x, fmaf(l1, Ab.y, Bab));
        c1 = fmaf(l0, Cb.x, fmaf(l1, Cb.y, Bcb));
        v1 += c0 + c1;
        v2 = fmaf(c0, c0, fmaf(c1, c1, v2));
        v1 = rowSumDpp(v1);
        v2 = rowSumDpp(v2);
        if ((lane & 15) == 15)
            red2[b][wave][lane >> 4] = make_float2(v1, v2);
    }
    __syncthreads();
    if (tid < 128) {   // slot = b*2+k = tid
        int b = tid >> 1, k = tid & 1;
        float s = 0;
#pragma unroll
        for (int w = 0; w < 4; ++w)
#pragma unroll
            for (int r = 0; r < 4; ++r)
                s += ((const float*)&red2[b][w][r])[k];
        part1[bid * 128 + tid] = s;
    }
}

// ---------------------------------------------------------------------------
// k2: main fused pass. 512 blocks (bd 16 x bu 32). Prologue: redundant fold of
// part1[512][128] (L2-hot) -> LN2 stats. Main: 2 d's/thread, quadSum DPP,
// lane-private LDS accumulators (no in-loop barriers), plain partial stores.
// ---------------------------------------------------------------------------
struct Wt { float2 W1, B1, G1, E1, A, C, G2, E2, W3; float Ba, Bc, B3, G3v; };

__global__ void __launch_bounds__(256) k2(
    const float* __restrict__ w1, const float* __restrict__ b1,
    const float* __restrict__ g1, const float* __restrict__ be1,
    const float* __restrict__ w21, const float* __restrict__ w22,
    const float* __restrict__ b21, const float* __restrict__ b22,
    const float* __restrict__ g2, const float* __restrict__ be2,
    const float* __restrict__ w3, const float* __restrict__ b3,
    const float* __restrict__ g3,
    const float* __restrict__ xnp, const float* __restrict__ rs1a,
    const float* __restrict__ mm1a, const float* __restrict__ part1,
    float* __restrict__ pp, float* __restrict__ qp) {
    int bu = blockIdx.x & 31, bd = blockIdx.x >> 5, tid = threadIdx.x;
    int lane = tid & 63, wave = tid >> 6;
    int ul = (lane >> 2) & 15, d0 = lane & 3;
    int u = bu * 16 + ul;
    int dl0 = wave * 8 + d0 * 2;
    __shared__ float4 sc[64];
    __shared__ float sxn[64][32];
    __shared__ float comb[4][64][16][3];   // [wave][b][u][stat] 48 KB
    __shared__ float tmp2[2][128];
    // prologue part A: fold part1 (slot s over 512 k1-blocks, split 2 ways)
    {
        int s = tid & 127, half = tid >> 7;
        float acc = 0;
        const float* p = part1 + half * 256 * 128 + s;
#pragma unroll 8
        for (int blk = 0; blk < 256; ++blk) acc += p[blk * 128];
        tmp2[half][s] = acc;
    }
    {
        float* cz = &comb[0][0][0][0];
        for (int t = tid; t < 4 * 64 * 16 * 3; t += 256) cz[t] = 0.f;
    }
    for (int idx = tid; idx < 2048; idx += 256)
        sxn[idx >> 5][idx & 31] = xnp[(idx >> 5) * 512 + bd * 32 + (idx & 31)];
    Wt wt[2];
#pragma unroll
    for (int j = 0; j < 2; ++j) {
        int d = bd * 32 + dl0 + j;
        int i = d * 512 + u;
        wt[j].W1 = ((const float2*)w1)[i];  wt[j].B1 = ((const float2*)b1)[i];
        wt[j].G1 = ((const float2*)g1)[i];  wt[j].E1 = ((const float2*)be1)[i];
        wt[j].A  = ((const float2*)w21)[i]; wt[j].C  = ((const float2*)w22)[i];
        wt[j].G2 = ((const float2*)g2)[i];  wt[j].E2 = ((const float2*)be2)[i];
        wt[j].W3 = ((const float2*)w3)[i];
        wt[j].Ba = b21[i]; wt[j].Bc = b22[i]; wt[j].B3 = b3[i]; wt[j].G3v = g3[i];
    }
    __syncthreads();
    // prologue part B: LN2 stats per batch
    if (tid < 64) {
        float ssum = tmp2[0][2 * tid] + tmp2[1][2 * tid];
        float s2sum = tmp2[0][2 * tid + 1] + tmp2[1][2 * tid + 1];
        float mm = ssum * INV_N1;
        float var = s2sum * INV_N1 - mm * mm;
        float r2 = rsqrtf(var + EPS);
        sc[tid] = make_float4(rs1a[tid], mm1a[tid], r2, mm * r2);
    }
    __syncthreads();
    for (int b = 0; b < 64; ++b) {
        float4 s4 = sc[b];   // rs1, m1*rs1, rs2, m2*rs2
        float p = 0, q = 0, q2 = 0;
#pragma unroll
        for (int j = 0; j < 2; ++j) {
            float xd = sxn[b][dl0 + j];
            float t0 = fmaf(xd, wt[j].W1.x, wt[j].B1.x), t1 = fmaf(xd, wt[j].W1.y, wt[j].B1.y);
            float z0 = fmaf(t0, s4.x, -s4.y), z1 = fmaf(t1, s4.x, -s4.y);
            float y0 = fmaf(z0, wt[j].G1.x, wt[j].E1.x), y1 = fmaf(z1, wt[j].G1.y, wt[j].E1.y);
            float l0 = lrelu(y0), l1 = lrelu(y1);
            float c0 = fmaf(l0, wt[j].A.x, fmaf(l1, wt[j].A.y, wt[j].Ba));
            float c1 = fmaf(l0, wt[j].C.x, fmaf(l1, wt[j].C.y, wt[j].Bc));
            float z20 = fmaf(c0, s4.z, -s4.w), z21 = fmaf(c1, s4.z, -s4.w);
            float y20 = fmaf(z20, wt[j].G2.x, wt[j].E2.x), y21 = fmaf(z21, wt[j].G2.y, wt[j].E2.y);
            float m0 = lrelu(y20), m1v = lrelu(y21);
            float l3 = fmaf(m0, wt[j].W3.x, fmaf(m1v, wt[j].W3.y, wt[j].B3));
            p = fmaf(l3, wt[j].G3v, p); q += l3; q2 = fmaf(l3, l3, q2);
        }
        p = quadSum(p); q = quadSum(q); q2 = quadSum(q2);
        if (d0 < 3) {
            float v = (d0 == 0) ? p : ((d0 == 1) ? q : q2);
            comb[wave][b][ul][d0] += v;   // lane-private slot
        }
    }
    __syncthreads();
    // fold p over waves -> per-(b,u) partial for this bd (plain store)
#pragma unroll
    for (int r = 0; r < 4; ++r) {
        int idx = r * 256 + tid;
        int b = idx >> 4, uu = idx & 15;
        float s = comb[0][b][uu][0] + comb[1][b][uu][0]
                + comb[2][b][uu][0] + comb[3][b][uu][0];
        pp[(bd * 64 + b) * 512 + bu * 16 + uu] = s;
    }
    // fold q,q2 over waves AND u -> per-(block,b) scalars (plain store)
    if (tid < 128) {
        int b = tid >> 1, st = 1 + (tid & 1);
        float s = 0;
#pragma unroll
        for (int w = 0; w < 4; ++w)
#pragma unroll
            for (int uu = 0; uu < 16; ++uu) s += comb[w][b][uu][st];
        qp[(bd * 32 + bu) * 128 + b * 2 + (st - 1)] = s;
    }
}

// ---------------------------------------------------------------------------
// k3: prologue folds Gp/Bp -> per-u G3s/Be3s (redundant per block); LN3 stats
// from q-partials; fold p-partials; finalize output.
// ---------------------------------------------------------------------------
__global__ void __launch_bounds__(512) k3(
    const float* __restrict__ pp, const float* __restrict__ qp,
    const float* __restrict__ Gp, const float* __restrict__ Bp,
    const float* __restrict__ Xs, const float* __restrict__ bias,
    float* __restrict__ out) {
    int b = blockIdx.x, u = threadIdx.x;
    float g3s = 0, be3s = 0;
#pragma unroll 8
    for (int jj = 0; jj < 64; ++jj) {
        g3s  += Gp[jj * 512 + u];
        be3s += Bp[jj * 512 + u];
    }
    float q  = qp[u * 128 + b * 2 + 0];
    float q2 = qp[u * 128 + b * 2 + 1];
    __shared__ float red[8][2];
    __shared__ float bc2[2];
    float sq = waveAllSum(q), sq2 = waveAllSum(q2);
    int wave = u >> 6, lane = u & 63;
    if (lane == 0) { red[wave][0] = sq; red[wave][1] = sq2; }
    __syncthreads();
    if (u == 0) {
        float a = 0, c = 0;
        for (int w = 0; w < 8; ++w) { a += red[w][0]; c += red[w][1]; }
        float m3 = a * INV_N3;
        float e3 = c * INV_N3;
        bc2[0] = m3; bc2[1] = rsqrtf(e3 - m3 * m3 + EPS);
    }
    __syncthreads();
    float p = 0;
#pragma unroll 4
    for (int bd = 0; bd < 16; ++bd) p += pp[(bd * 64 + b) * 512 + u];
    float m3 = bc2[0], rs3 = bc2[1];
    float val = rs3 * (p - m3 * g3s) + be3s + Xs[b] + bias[u];
    out[b * 512 + u] = lrelu(val);
}

extern "C" void kernel_launch(void* const* d_in, const int* in_sizes, int n_in,
                              void* d_out, int out_size, void* d_ws, size_t ws_size,
                              hipStream_t stream) {
    const float* x   = (const float*)d_in[0];
    const float* w1  = (const float*)d_in[1];
    const float* b1  = (const float*)d_in[2];
    const float* w21 = (const float*)d_in[3];
    const float* w22 = (const float*)d_in[4];
    const float* b21 = (const float*)d_in[5];
    const float* b22 = (const float*)d_in[6];
    const float* w3  = (const float*)d_in[7];
    const float* b3  = (const float*)d_in[8];
    const float* bias= (const float*)d_in[9];
    const float* g0  = (const float*)d_in[10];
    const float* be0 = (const float*)d_in[11];
    const float* g1  = (const float*)d_in[12];
    const float* be1 = (const float*)d_in[13];
    const float* g2  = (const float*)d_in[14];
    const float* be2 = (const float*)d_in[15];
    const float* g3  = (const float*)d_in[16];
    const float* be3 = (const float*)d_in[17];
    float* out = (float*)d_out;
    char* ws = (char*)d_ws;

    float* xn    = (float*)(ws);             // 131072  [B][D]
    float* S1    = (float*)(ws + 131072);
    float* S2    = (float*)(ws + 133120);
    float* S11   = (float*)(ws + 135168);
    float* S0b   = (float*)(ws + 137216);
    float* Sb2   = (float*)(ws + 139264);
    float* rs1a  = (float*)(ws + 141312);
    float* mm1a  = (float*)(ws + 141568);
    float* Xs    = (float*)(ws + 141824);
    float* Gp    = (float*)(ws + 146176);    // 131072 [64][512]
    float* Bp    = (float*)(ws + 277248);    // 131072
    float* part1 = (float*)(ws + 408320);    // 262144 [512][128]
    float* qp    = (float*)(ws + 670464);    // 262144 [512][128]
    float* pp    = (float*)(ws + 932608);    // 2097152 [16][64][512]

    hipLaunchKernelGGL(kA, dim3(640), dim3(256), 0, stream,
                       w1, b1, g3, be3, x, g0, be0,
                       S1, S2, S11, S0b, Sb2, Gp, Bp, xn, Xs);
    hipLaunchKernelGGL(k1, dim3(512), dim3(256), 0, stream,
                       w1, b1, g1, be1, w21, w22, b21, b22, xn,
                       S1, S2, S11, S0b, Sb2, rs1a, mm1a, part1);
    hipLaunchKernelGGL(k2, dim3(512), dim3(256), 0, stream,
                       w1, b1, g1, be1, w21, w22, b21, b22, g2, be2, w3, b3, g3,
                       xn, rs1a, mm1a, part1, pp, qp);
    hipLaunchKernelGGL(k3, dim3(64), dim3(512), 0, stream,
                       pp, qp, Gp, Bp, Xs, bias, out);
}